// Round 15
// baseline (77.754 us; speedup 1.0000x reference)
//
#include <hip/hip_runtime.h>

#define D_DIM 1024
#define H_DIM 64
#define T_SEQ 2048
#define B_SZ  8
#define M_TOT (B_SZ * T_SEQ)

typedef __attribute__((ext_vector_type(4))) float f32x4;
typedef __attribute__((ext_vector_type(8))) short s16x8;
typedef __attribute__((ext_vector_type(8))) unsigned short u16x8;
typedef __attribute__((ext_vector_type(4))) unsigned short u16x4;

__device__ __forceinline__ unsigned short f2bf(float x) {
    union { float f; unsigned u; } v; v.f = x;
    unsigned r = (v.u + 0x7FFFu + ((v.u >> 16) & 1u)) >> 16;   // RNE
    return (unsigned short)r;
}
__device__ __forceinline__ float bf2f(unsigned short u) {
    union { unsigned u; float f; } v; v.u = ((unsigned)u) << 16; return v.f;
}
__device__ __forceinline__ f32x4 mfma_bf16(u16x8 a, u16x8 b, f32x4 c) {
    return __builtin_amdgcn_mfma_f32_16x16x32_bf16(
        __builtin_bit_cast(s16x8, a), __builtin_bit_cast(s16x8, b), c, 0, 0, 0);
}

// ---------------------------------------------------------------------------
// Kernel 0: W fp32 [1024][64] (x3) -> WF bf16 in MFMA B-fragment order.
// fid = ks*24 + (mat*4+colTile)*2 + kh ; each fragment = contiguous 1KB.
// (proven since round 9)
// ---------------------------------------------------------------------------
__global__ __launch_bounds__(256) void wtrans_kernel(
    const float* __restrict__ Wq, const float* __restrict__ Wk,
    const float* __restrict__ Wv, unsigned short* __restrict__ WF)
{
    __shared__ unsigned short tw[64 * 72];
    const int mat = blockIdx.x / 16;
    const int k0  = (blockIdx.x % 16) * 64;
    const int ks  = k0 >> 6;
    const float* W = (mat == 0) ? Wq : (mat == 1) ? Wk : Wv;
    const int tid = threadIdx.x;

    {
        const int r = tid >> 2, c0 = (tid & 3) * 16;
        #pragma unroll
        for (int jj = 0; jj < 4; ++jj) {
            float4 v = *reinterpret_cast<const float4*>(&W[(size_t)(k0 + r) * H_DIM + c0 + jj * 4]);
            u16x4 u = { f2bf(v.x), f2bf(v.y), f2bf(v.z), f2bf(v.w) };
            *reinterpret_cast<u16x4*>(&tw[r * 72 + c0 + jj * 4]) = u;
        }
    }
    __syncthreads();
    #pragma unroll
    for (int sb = 0; sb < 2; ++sb) {
        const int s    = sb * 256 + tid;
        const int ct_l = s >> 7;
        const int kh   = (s >> 6) & 1;
        const int lane = s & 63;
        const int gg = lane >> 4, nn = lane & 15;
        const int cl = ct_l * 16 + nn;
        const int kl = kh * 32 + gg * 8;
        unsigned short tmp[8];
        #pragma unroll
        for (int t = 0; t < 8; ++t) tmp[t] = tw[(kl + t) * 72 + cl];
        const int fid = ks * 24 + (mat * 4 + ct_l) * 2 + kh;
        *reinterpret_cast<u16x8*>(&WF[((size_t)fid * 64 + lane) * 8]) =
            *reinterpret_cast<const u16x8*>(tmp);
    }
}

// ---------------------------------------------------------------------------
// Kernel 1: x fp32 -> bf16, pure m13-style grid-stride stream.
// 2048 blocks x 256 thr x 4 iters = 2,097,152 u16x8 outputs = ALL of x.
// (round-14 bug: 2 iters covered only half of x)
// ---------------------------------------------------------------------------
__global__ __launch_bounds__(256) void convert_kernel(
    const float* __restrict__ x, unsigned short* __restrict__ xb)
{
    const float4* x4 = reinterpret_cast<const float4*>(x);
    const unsigned idx = blockIdx.x * 256 + threadIdx.x;   // 0..524287
    #pragma unroll
    for (int it = 0; it < 4; ++it) {
        const size_t j = idx + (size_t)it * 524288;        // u16x8 index, 0..2097151
        const float4 a = x4[2 * j];
        const float4 b = x4[2 * j + 1];
        u16x8 v = { f2bf(a.x), f2bf(a.y), f2bf(a.z), f2bf(a.w),
                    f2bf(b.x), f2bf(b.y), f2bf(b.z), f2bf(b.w) };
        *reinterpret_cast<u16x8*>(&xb[j * 8]) = v;
    }
}

// ---------------------------------------------------------------------------
// Kernel 2: QKV projection v11 — ZERO-LDS K-loop.
// A-frags: per-lane u16x8 direct from bf16 x (wave = 16 rows x 64B segments).
// B-frags: coalesced 1KB WFRAG loads (L2-resident).
// 16 fully-unrolled iters, 1-deep dual prefetch, NO barriers, NO ds ops.
// LDS only for the 3KB vt epilogue transpose.
// ---------------------------------------------------------------------------
__global__ __launch_bounds__(256) void qkv_proj_kernel(
    const unsigned short* __restrict__ xb, const unsigned short* __restrict__ WF,
    unsigned short* __restrict__ Qg, unsigned short* __restrict__ Kg,
    unsigned short* __restrict__ Vtg)
{
    __shared__ unsigned short vt[64 * 24];     // epilogue V transpose only

    const int tid = threadIdx.x;
    const int w = tid >> 6, l = tid & 63, g = l >> 4, n = l & 15;
    const int m0 = blockIdx.x * 16;

    // per-lane A-frag pointer: row m0+n, k-slot g*8; af(ks,kh) at +ks*64+kh*32
    const unsigned short* xlane = xb + (size_t)(m0 + n) * D_DIM + g * 8;
    // per-wave B-frag base (fragment-ordered WF)
    const unsigned short* wfb = WF + ((size_t)(w * 3) * 2 * 64 + l) * 8;
#define WFRAG(ks, ct, kh) \
    (*reinterpret_cast<const u16x8*>(wfb + (((ks) * 24 + (ct) * 2 + (kh)) * 64) * 8))
#define AFRAG(ks, kh) \
    (*reinterpret_cast<const u16x8*>(xlane + (ks) * 64 + (kh) * 32))

    // prefetch iter 0
    u16x8 ca0 = AFRAG(0, 0), ca1 = AFRAG(0, 1);
    u16x8 cw00 = WFRAG(0, 0, 0), cw10 = WFRAG(0, 1, 0), cw20 = WFRAG(0, 2, 0);
    u16x8 cw01 = WFRAG(0, 0, 1), cw11 = WFRAG(0, 1, 1), cw21 = WFRAG(0, 2, 1);

    f32x4 acc0 = {0.f,0.f,0.f,0.f}, acc1 = {0.f,0.f,0.f,0.f}, acc2 = {0.f,0.f,0.f,0.f};

    #pragma unroll
    for (int ks = 0; ks < 16; ++ks) {
        const u16x8 a0 = ca0, a1 = ca1;
        const u16x8 u00 = cw00, u10 = cw10, u20 = cw20;
        const u16x8 u01 = cw01, u11 = cw11, u21 = cw21;
        if (ks < 15) {
            ca0 = AFRAG(ks + 1, 0);  ca1 = AFRAG(ks + 1, 1);
            cw00 = WFRAG(ks + 1, 0, 0); cw10 = WFRAG(ks + 1, 1, 0);
            cw20 = WFRAG(ks + 1, 2, 0); cw01 = WFRAG(ks + 1, 0, 1);
            cw11 = WFRAG(ks + 1, 1, 1); cw21 = WFRAG(ks + 1, 2, 1);
        }
        acc0 = mfma_bf16(a0, u00, acc0);
        acc1 = mfma_bf16(a0, u10, acc1);
        acc2 = mfma_bf16(a0, u20, acc2);
        acc0 = mfma_bf16(a1, u01, acc0);
        acc1 = mfma_bf16(a1, u11, acc1);
        acc2 = mfma_bf16(a1, u21, acc2);
    }
#undef WFRAG
#undef AFRAG

    // ---- epilogue: D layout col = lane&15, row = (lane>>4)*4 + reg ----
    const int b = m0 >> 11, t0 = m0 & (T_SEQ - 1);
    const f32x4 accs[3] = { acc0, acc1, acc2 };
    #pragma unroll
    for (int ct = 0; ct < 3; ++ct) {
        const int c = w * 48 + ct * 16 + n;
        #pragma unroll
        for (int r = 0; r < 4; ++r) {
            const int rin = g * 4 + r;
            const float val = accs[ct][r];
            if (c < 64)
                Qg[(size_t)(m0 + rin) * H_DIM + c] = f2bf(val * 0.125f);
            else if (c < 128)
                Kg[(size_t)(m0 + rin) * H_DIM + (c - 64)] = f2bf(val);
            else
                vt[(c - 128) * 24 + rin] = f2bf(val);
        }
    }
    __syncthreads();
    {   // Vt[b][h][t]: 64h x 16t, one u16x4 per thread
        const int h = tid >> 2, c4 = (tid & 3) * 4;
        *reinterpret_cast<u16x4*>(&Vtg[((size_t)(b * 64 + h)) * T_SEQ + t0 + c4]) =
            *reinterpret_cast<const u16x4*>(&vt[h * 24 + c4]);
    }
}

// ---------------------------------------------------------------------------
// Kernel 3: causal flash attention (unchanged PASS since round 5).
// ---------------------------------------------------------------------------
__global__ __launch_bounds__(256) void attn_kernel(
    const unsigned short* __restrict__ Qg, const unsigned short* __restrict__ Kg,
    const unsigned short* __restrict__ Vtg, float* __restrict__ out)
{
    __shared__ unsigned short Kl[128 * 72];   // [key][h]
    __shared__ unsigned short Vl[64 * 136];   // [h][key]
    __shared__ float Om[2][64][20];           // merge buffer
    __shared__ float mred[4][64], lred[4][64];

    const int tid = threadIdx.x;
    const int wv = tid >> 6, qg = wv >> 1, kh = wv & 1;
    const int l = tid & 63, g = l >> 4, n = l & 15;

    const int i = blockIdx.x, hi = i >> 8, rest = i & 255;
    const int b = hi * 4 + (rest >> 6), j = rest & 63;
    const int qt = hi ? (63 - j) : j;
    const int q0 = qt * 32;
    const int qrow = q0 + qg * 16 + n;
    const int qmax = q0 + qg * 16 + 15;
    const int nk = (qt >> 2) + 1;

    const unsigned short* Qb = Qg + (size_t)b * T_SEQ * H_DIM;
    const unsigned short* Kb = Kg + (size_t)b * T_SEQ * H_DIM;
    const unsigned short* Vb = Vtg + (size_t)b * H_DIM * T_SEQ;

    const u16x8 qf0 = *reinterpret_cast<const u16x8*>(&Qb[(size_t)qrow * H_DIM + g * 8]);
    const u16x8 qf1 = *reinterpret_cast<const u16x8*>(&Qb[(size_t)qrow * H_DIM + 32 + g * 8]);

    f32x4 oacc[4];
    #pragma unroll
    for (int hb = 0; hb < 4; ++hb) oacc[hb] = f32x4{0.f, 0.f, 0.f, 0.f};
    float mrun = -1e30f, lrun = 0.f;

    u16x8 kst[4], vst[4];
    #pragma unroll
    for (int ii = 0; ii < 4; ++ii) {
        const int u = tid + ii * 256;
        const int kr = u >> 3, kc = (u & 7) * 8;
        const int vh = u >> 4, vc = (u & 15) * 8;
        kst[ii] = *reinterpret_cast<const u16x8*>(&Kb[(size_t)kr * H_DIM + kc]);
        vst[ii] = *reinterpret_cast<const u16x8*>(&Vb[(size_t)vh * T_SEQ + vc]);
    }

    for (int t = 0; t < nk; ++t) {
        __syncthreads();
        #pragma unroll
        for (int ii = 0; ii < 4; ++ii) {
            const int u = tid + ii * 256;
            const int kr = u >> 3, kc = (u & 7) * 8;
            const int vh = u >> 4, vc = (u & 15) * 8;
            *reinterpret_cast<u16x8*>(&Kl[kr * 72 + kc]) = kst[ii];
            *reinterpret_cast<u16x8*>(&Vl[vh * 136 + vc]) = vst[ii];
        }
        __syncthreads();
        if (t + 1 < nk) {
            const int k0n = (t + 1) * 128;
            #pragma unroll
            for (int ii = 0; ii < 4; ++ii) {
                const int u = tid + ii * 256;
                const int kr = u >> 3, kc = (u & 7) * 8;
                const int vh = u >> 4, vc = (u & 15) * 8;
                kst[ii] = *reinterpret_cast<const u16x8*>(&Kb[(size_t)(k0n + kr) * H_DIM + kc]);
                vst[ii] = *reinterpret_cast<const u16x8*>(&Vb[(size_t)vh * T_SEQ + k0n + vc]);
            }
        }

        const int kbase = kh * 64;
        if (t * 128 + kbase <= qmax) {
            f32x4 s[4];
            #pragma unroll
            for (int kb = 0; kb < 4; ++kb) {
                const u16x8 kf0 = *reinterpret_cast<const u16x8*>(&Kl[(kbase + kb * 16 + n) * 72 + g * 8]);
                const u16x8 kf1 = *reinterpret_cast<const u16x8*>(&Kl[(kbase + kb * 16 + n) * 72 + 32 + g * 8]);
                f32x4 z = f32x4{0.f, 0.f, 0.f, 0.f};
                z = mfma_bf16(kf0, qf0, z);
                z = mfma_bf16(kf1, qf1, z);
                s[kb] = z;
            }

            float sv[16];
            float tmax = -1e30f;
            #pragma unroll
            for (int kb = 0; kb < 4; ++kb)
                #pragma unroll
                for (int r = 0; r < 4; ++r) {
                    const int kk = t * 128 + kbase + kb * 16 + g * 4 + r;
                    float v = s[kb][r];
                    v = (kk <= qrow) ? v : -1e30f;
                    sv[kb * 4 + r] = v;
                    tmax = fmaxf(tmax, v);
                }
            tmax = fmaxf(tmax, __shfl_xor(tmax, 16));
            tmax = fmaxf(tmax, __shfl_xor(tmax, 32));
            const float mnew = fmaxf(mrun, tmax);
            const float scale = __expf(mrun - mnew);
            #pragma unroll
            for (int hb = 0; hb < 4; ++hb) oacc[hb] *= scale;
            lrun = lrun * scale;
            mrun = mnew;

            unsigned short pb[16];
            float ps = 0.f;
            #pragma unroll
            for (int q = 0; q < 16; ++q) {
                const float p = (sv[q] > -1e29f) ? __expf(sv[q] - mnew) : 0.f;
                pb[q] = f2bf(p);
                ps += bf2f(pb[q]);
            }
            ps += __shfl_xor(ps, 16);
            ps += __shfl_xor(ps, 32);
            lrun += ps;

            u16x8 pa0, pa1;
            #pragma unroll
            for (int q = 0; q < 8; ++q) { pa0[q] = pb[q]; pa1[q] = pb[8 + q]; }

            #pragma unroll
            for (int hb = 0; hb < 4; ++hb) {
                const unsigned short* vp = &Vl[(hb * 16 + n) * 136 + kbase + 4 * g];
                const u16x4 a0 = *reinterpret_cast<const u16x4*>(vp);
                const u16x4 a1 = *reinterpret_cast<const u16x4*>(vp + 16);
                const u16x4 b0 = *reinterpret_cast<const u16x4*>(vp + 32);
                const u16x4 b1 = *reinterpret_cast<const u16x4*>(vp + 48);
                const u16x8 vf0 = { a0[0], a0[1], a0[2], a0[3], a1[0], a1[1], a1[2], a1[3] };
                const u16x8 vf1 = { b0[0], b0[1], b0[2], b0[3], b1[0], b1[1], b1[2], b1[3] };
                oacc[hb] = mfma_bf16(vf0, pa0, oacc[hb]);
                oacc[hb] = mfma_bf16(vf1, pa1, oacc[hb]);
            }
        }
    }

    // cross-wave (kh pair) merge
    mred[wv][l] = mrun;
    lred[wv][l] = lrun;
    __syncthreads();
    const float m0v = mred[qg * 2][l],     l0v = lred[qg * 2][l];
    const float m1v = mred[qg * 2 + 1][l], l1v = lred[qg * 2 + 1][l];
    const float M = fmaxf(m0v, m1v);
    const float alpha = __expf(mrun - M);
    const float Lsum = l0v * __expf(m0v - M) + l1v * __expf(m1v - M);
    #pragma unroll
    for (int hb = 0; hb < 4; ++hb) oacc[hb] *= alpha;

    if (kh == 1) {
        #pragma unroll
        for (int hb = 0; hb < 4; ++hb)
            *reinterpret_cast<f32x4*>(&Om[qg][l][hb * 4]) = oacc[hb];
    }
    __syncthreads();
    if (kh == 0) {
        const float inv = 1.0f / Lsum;
        #pragma unroll
        for (int hb = 0; hb < 4; ++hb) {
            const f32x4 o2 = *reinterpret_cast<const f32x4*>(&Om[qg][l][hb * 4]);
            float4 o;
            o.x = (oacc[hb][0] + o2[0]) * inv;
            o.y = (oacc[hb][1] + o2[1]) * inv;
            o.z = (oacc[hb][2] + o2[2]) * inv;
            o.w = (oacc[hb][3] + o2[3]) * inv;
            *reinterpret_cast<float4*>(
                &out[((size_t)b * T_SEQ + qrow) * H_DIM + hb * 16 + 4 * g]) = o;
        }
    }
}

// ---------------------------------------------------------------------------
extern "C" void kernel_launch(void* const* d_in, const int* in_sizes, int n_in,
                              void* d_out, int out_size, void* d_ws, size_t ws_size,
                              hipStream_t stream) {
    const float* x  = (const float*)d_in[0];
    const float* Wq = (const float*)d_in[1];
    const float* Wk = (const float*)d_in[2];
    const float* Wv = (const float*)d_in[3];

    unsigned short* Qg  = (unsigned short*)d_ws;
    unsigned short* Kg  = Qg + (size_t)M_TOT * H_DIM;
    unsigned short* Vtg = Kg + (size_t)M_TOT * H_DIM;
    unsigned short* WF  = Vtg + (size_t)M_TOT * H_DIM;       // 384 KB
    unsigned short* xb  = WF + (size_t)16 * 24 * 64 * 8;     // 32 MB bf16 x
    float* o = (float*)d_out;

    wtrans_kernel<<<48, 256, 0, stream>>>(Wq, Wk, Wv, WF);
    convert_kernel<<<2048, 256, 0, stream>>>(x, xb);
    qkv_proj_kernel<<<M_TOT / 16, 256, 0, stream>>>(xb, WF, Qg, Kg, Vtg);
    attn_kernel<<<512, 256, 0, stream>>>(Qg, Kg, Vtg, o);
}

// Round 17
// 72.997 us; speedup vs baseline: 1.0652x; 1.0652x over previous
//
#include <hip/hip_runtime.h>

#define D_DIM 1024
#define H_DIM 64
#define T_SEQ 2048
#define B_SZ  8
#define M_TOT (B_SZ * T_SEQ)

typedef __attribute__((ext_vector_type(4))) float f32x4;
typedef __attribute__((ext_vector_type(8))) short s16x8;
typedef __attribute__((ext_vector_type(8))) unsigned short u16x8;
typedef __attribute__((ext_vector_type(4))) unsigned short u16x4;

__device__ __forceinline__ unsigned short f2bf(float x) {
    union { float f; unsigned u; } v; v.f = x;
    unsigned r = (v.u + 0x7FFFu + ((v.u >> 16) & 1u)) >> 16;   // RNE
    return (unsigned short)r;
}
__device__ __forceinline__ float bf2f(unsigned short u) {
    union { unsigned u; float f; } v; v.u = ((unsigned)u) << 16; return v.f;
}
__device__ __forceinline__ f32x4 mfma_bf16(u16x8 a, u16x8 b, f32x4 c) {
    return __builtin_amdgcn_mfma_f32_16x16x32_bf16(
        __builtin_bit_cast(s16x8, a), __builtin_bit_cast(s16x8, b), c, 0, 0, 0);
}

// ---------------------------------------------------------------------------
// Kernel 0: W fp32 [1024][64] (x3) -> WF bf16 in MFMA B-fragment order.
// fid = ks*24 + (mat*4+colTile)*2 + kh ; each fragment = contiguous 1KB.
// (proven since round 9)
// ---------------------------------------------------------------------------
__global__ __launch_bounds__(256) void wtrans_kernel(
    const float* __restrict__ Wq, const float* __restrict__ Wk,
    const float* __restrict__ Wv, unsigned short* __restrict__ WF)
{
    __shared__ unsigned short tw[64 * 72];
    const int mat = blockIdx.x / 16;
    const int k0  = (blockIdx.x % 16) * 64;
    const int ks  = k0 >> 6;
    const float* W = (mat == 0) ? Wq : (mat == 1) ? Wk : Wv;
    const int tid = threadIdx.x;

    {
        const int r = tid >> 2, c0 = (tid & 3) * 16;
        #pragma unroll
        for (int jj = 0; jj < 4; ++jj) {
            float4 v = *reinterpret_cast<const float4*>(&W[(size_t)(k0 + r) * H_DIM + c0 + jj * 4]);
            u16x4 u = { f2bf(v.x), f2bf(v.y), f2bf(v.z), f2bf(v.w) };
            *reinterpret_cast<u16x4*>(&tw[r * 72 + c0 + jj * 4]) = u;
        }
    }
    __syncthreads();
    #pragma unroll
    for (int sb = 0; sb < 2; ++sb) {
        const int s    = sb * 256 + tid;
        const int ct_l = s >> 7;
        const int kh   = (s >> 6) & 1;
        const int lane = s & 63;
        const int gg = lane >> 4, nn = lane & 15;
        const int cl = ct_l * 16 + nn;
        const int kl = kh * 32 + gg * 8;
        unsigned short tmp[8];
        #pragma unroll
        for (int t = 0; t < 8; ++t) tmp[t] = tw[(kl + t) * 72 + cl];
        const int fid = ks * 24 + (mat * 4 + ct_l) * 2 + kh;
        *reinterpret_cast<u16x8*>(&WF[((size_t)fid * 64 + lane) * 8]) =
            *reinterpret_cast<const u16x8*>(tmp);
    }
}

// ---------------------------------------------------------------------------
// Kernel 1: QKV projection v12b = round-13 v9 + NON-TEMPORAL loads
// (ext_vector f32x4 this time — __builtin_nontemporal_load rejects
// HIP_vector_type). Single-variable A/B vs round-13's 57.5us.
// ---------------------------------------------------------------------------
__global__ __launch_bounds__(256, 4) void qkv_proj_kernel(
    const float* __restrict__ x, const unsigned short* __restrict__ WF,
    unsigned short* __restrict__ Qg, unsigned short* __restrict__ Kg,
    unsigned short* __restrict__ Vtg)
{
    __shared__ unsigned short xs[16 * 1040];   // [16][1024+16] bf16 = 33280 B
    __shared__ unsigned short vt[64 * 24];     // epilogue V transpose

    const int tid = threadIdx.x;
    const int w = tid >> 6, l = tid & 63, g = l >> 4, n = l & 15;
    const int m0 = blockIdx.x * 16;

    // ---- stage whole 16x1024 x panel: 16 nt f32x4/thread, single burst ----
    {
        const f32x4* x4 = reinterpret_cast<const f32x4*>(x + (size_t)m0 * D_DIM);
        f32x4 st[16];
        #pragma unroll
        for (int j = 0; j < 16; ++j)
            st[j] = __builtin_nontemporal_load(&x4[j * 256 + tid]);
        #pragma unroll
        for (int j = 0; j < 16; ++j) {
            const int u = j * 256 + tid;            // f32x4 unit 0..4095
            const int row = u >> 8, col = (u & 255) * 4;
            u16x4 v = { f2bf(st[j][0]), f2bf(st[j][1]), f2bf(st[j][2]), f2bf(st[j][3]) };
            *reinterpret_cast<u16x4*>(&xs[row * 1040 + col]) = v;
        }
    }
    __syncthreads();   // the ONLY pre-epilogue barrier

    // ---- barrier-free K-loop; nt W frags direct from WF ----
    const unsigned short* wfb = WF + ((size_t)(w * 3) * 2 * 64 + l) * 8;
#define WFRAG(ks, ct, kh) \
    (__builtin_nontemporal_load(reinterpret_cast<const u16x8*>( \
        wfb + (((ks) * 24 + (ct) * 2 + (kh)) * 64) * 8)))

    u16x8 cw00 = WFRAG(0, 0, 0), cw10 = WFRAG(0, 1, 0), cw20 = WFRAG(0, 2, 0);
    u16x8 cw01 = WFRAG(0, 0, 1), cw11 = WFRAG(0, 1, 1), cw21 = WFRAG(0, 2, 1);

    f32x4 acc0 = {0.f,0.f,0.f,0.f}, acc1 = {0.f,0.f,0.f,0.f}, acc2 = {0.f,0.f,0.f,0.f};

    #pragma unroll
    for (int ks = 0; ks < 16; ++ks) {
        const u16x8 u00 = cw00, u10 = cw10, u20 = cw20;
        const u16x8 u01 = cw01, u11 = cw11, u21 = cw21;
        if (ks < 15) {
            cw00 = WFRAG(ks + 1, 0, 0); cw10 = WFRAG(ks + 1, 1, 0);
            cw20 = WFRAG(ks + 1, 2, 0); cw01 = WFRAG(ks + 1, 0, 1);
            cw11 = WFRAG(ks + 1, 1, 1); cw21 = WFRAG(ks + 1, 2, 1);
        }
        const u16x8 af0 = *reinterpret_cast<const u16x8*>(&xs[n * 1040 + ks * 64 + g * 8]);
        const u16x8 af1 = *reinterpret_cast<const u16x8*>(&xs[n * 1040 + ks * 64 + 32 + g * 8]);
        acc0 = mfma_bf16(af0, u00, acc0);
        acc1 = mfma_bf16(af0, u10, acc1);
        acc2 = mfma_bf16(af0, u20, acc2);
        acc0 = mfma_bf16(af1, u01, acc0);
        acc1 = mfma_bf16(af1, u11, acc1);
        acc2 = mfma_bf16(af1, u21, acc2);
    }
#undef WFRAG

    // ---- epilogue: D layout col = lane&15, row = (lane>>4)*4 + reg ----
    const int b = m0 >> 11, t0 = m0 & (T_SEQ - 1);
    const f32x4 accs[3] = { acc0, acc1, acc2 };
    #pragma unroll
    for (int ct = 0; ct < 3; ++ct) {
        const int c = w * 48 + ct * 16 + n;
        #pragma unroll
        for (int r = 0; r < 4; ++r) {
            const int rin = g * 4 + r;
            const float val = accs[ct][r];
            if (c < 64)
                Qg[(size_t)(m0 + rin) * H_DIM + c] = f2bf(val * 0.125f);
            else if (c < 128)
                Kg[(size_t)(m0 + rin) * H_DIM + (c - 64)] = f2bf(val);
            else
                vt[(c - 128) * 24 + rin] = f2bf(val);
        }
    }
    __syncthreads();
    {   // Vt[b][h][t]: 64h x 16t, one u16x4 per thread
        const int h = tid >> 2, c4 = (tid & 3) * 4;
        *reinterpret_cast<u16x4*>(&Vtg[((size_t)(b * 64 + h)) * T_SEQ + t0 + c4]) =
            *reinterpret_cast<const u16x4*>(&vt[h * 24 + c4]);
    }
}

// ---------------------------------------------------------------------------
// Kernel 2: causal flash attention (unchanged PASS since round 5).
// ---------------------------------------------------------------------------
__global__ __launch_bounds__(256) void attn_kernel(
    const unsigned short* __restrict__ Qg, const unsigned short* __restrict__ Kg,
    const unsigned short* __restrict__ Vtg, float* __restrict__ out)
{
    __shared__ unsigned short Kl[128 * 72];   // [key][h]
    __shared__ unsigned short Vl[64 * 136];   // [h][key]
    __shared__ float Om[2][64][20];           // merge buffer
    __shared__ float mred[4][64], lred[4][64];

    const int tid = threadIdx.x;
    const int wv = tid >> 6, qg = wv >> 1, kh = wv & 1;
    const int l = tid & 63, g = l >> 4, n = l & 15;

    const int i = blockIdx.x, hi = i >> 8, rest = i & 255;
    const int b = hi * 4 + (rest >> 6), j = rest & 63;
    const int qt = hi ? (63 - j) : j;
    const int q0 = qt * 32;
    const int qrow = q0 + qg * 16 + n;
    const int qmax = q0 + qg * 16 + 15;
    const int nk = (qt >> 2) + 1;

    const unsigned short* Qb = Qg + (size_t)b * T_SEQ * H_DIM;
    const unsigned short* Kb = Kg + (size_t)b * T_SEQ * H_DIM;
    const unsigned short* Vb = Vtg + (size_t)b * H_DIM * T_SEQ;

    const u16x8 qf0 = *reinterpret_cast<const u16x8*>(&Qb[(size_t)qrow * H_DIM + g * 8]);
    const u16x8 qf1 = *reinterpret_cast<const u16x8*>(&Qb[(size_t)qrow * H_DIM + 32 + g * 8]);

    f32x4 oacc[4];
    #pragma unroll
    for (int hb = 0; hb < 4; ++hb) oacc[hb] = f32x4{0.f, 0.f, 0.f, 0.f};
    float mrun = -1e30f, lrun = 0.f;

    u16x8 kst[4], vst[4];
    #pragma unroll
    for (int ii = 0; ii < 4; ++ii) {
        const int u = tid + ii * 256;
        const int kr = u >> 3, kc = (u & 7) * 8;
        const int vh = u >> 4, vc = (u & 15) * 8;
        kst[ii] = *reinterpret_cast<const u16x8*>(&Kb[(size_t)kr * H_DIM + kc]);
        vst[ii] = *reinterpret_cast<const u16x8*>(&Vb[(size_t)vh * T_SEQ + vc]);
    }

    for (int t = 0; t < nk; ++t) {
        __syncthreads();
        #pragma unroll
        for (int ii = 0; ii < 4; ++ii) {
            const int u = tid + ii * 256;
            const int kr = u >> 3, kc = (u & 7) * 8;
            const int vh = u >> 4, vc = (u & 15) * 8;
            *reinterpret_cast<u16x8*>(&Kl[kr * 72 + kc]) = kst[ii];
            *reinterpret_cast<u16x8*>(&Vl[vh * 136 + vc]) = vst[ii];
        }
        __syncthreads();
        if (t + 1 < nk) {
            const int k0n = (t + 1) * 128;
            #pragma unroll
            for (int ii = 0; ii < 4; ++ii) {
                const int u = tid + ii * 256;
                const int kr = u >> 3, kc = (u & 7) * 8;
                const int vh = u >> 4, vc = (u & 15) * 8;
                kst[ii] = *reinterpret_cast<const u16x8*>(&Kb[(size_t)(k0n + kr) * H_DIM + kc]);
                vst[ii] = *reinterpret_cast<const u16x8*>(&Vb[(size_t)vh * T_SEQ + k0n + vc]);
            }
        }

        const int kbase = kh * 64;
        if (t * 128 + kbase <= qmax) {
            f32x4 s[4];
            #pragma unroll
            for (int kb = 0; kb < 4; ++kb) {
                const u16x8 kf0 = *reinterpret_cast<const u16x8*>(&Kl[(kbase + kb * 16 + n) * 72 + g * 8]);
                const u16x8 kf1 = *reinterpret_cast<const u16x8*>(&Kl[(kbase + kb * 16 + n) * 72 + 32 + g * 8]);
                f32x4 z = f32x4{0.f, 0.f, 0.f, 0.f};
                z = mfma_bf16(kf0, qf0, z);
                z = mfma_bf16(kf1, qf1, z);
                s[kb] = z;
            }

            float sv[16];
            float tmax = -1e30f;
            #pragma unroll
            for (int kb = 0; kb < 4; ++kb)
                #pragma unroll
                for (int r = 0; r < 4; ++r) {
                    const int kk = t * 128 + kbase + kb * 16 + g * 4 + r;
                    float v = s[kb][r];
                    v = (kk <= qrow) ? v : -1e30f;
                    sv[kb * 4 + r] = v;
                    tmax = fmaxf(tmax, v);
                }
            tmax = fmaxf(tmax, __shfl_xor(tmax, 16));
            tmax = fmaxf(tmax, __shfl_xor(tmax, 32));
            const float mnew = fmaxf(mrun, tmax);
            const float scale = __expf(mrun - mnew);
            #pragma unroll
            for (int hb = 0; hb < 4; ++hb) oacc[hb] *= scale;
            lrun = lrun * scale;
            mrun = mnew;

            unsigned short pb[16];
            float ps = 0.f;
            #pragma unroll
            for (int q = 0; q < 16; ++q) {
                const float p = (sv[q] > -1e29f) ? __expf(sv[q] - mnew) : 0.f;
                pb[q] = f2bf(p);
                ps += bf2f(pb[q]);
            }
            ps += __shfl_xor(ps, 16);
            ps += __shfl_xor(ps, 32);
            lrun += ps;

            u16x8 pa0, pa1;
            #pragma unroll
            for (int q = 0; q < 8; ++q) { pa0[q] = pb[q]; pa1[q] = pb[8 + q]; }

            #pragma unroll
            for (int hb = 0; hb < 4; ++hb) {
                const unsigned short* vp = &Vl[(hb * 16 + n) * 136 + kbase + 4 * g];
                const u16x4 a0 = *reinterpret_cast<const u16x4*>(vp);
                const u16x4 a1 = *reinterpret_cast<const u16x4*>(vp + 16);
                const u16x4 b0 = *reinterpret_cast<const u16x4*>(vp + 32);
                const u16x4 b1 = *reinterpret_cast<const u16x4*>(vp + 48);
                const u16x8 vf0 = { a0[0], a0[1], a0[2], a0[3], a1[0], a1[1], a1[2], a1[3] };
                const u16x8 vf1 = { b0[0], b0[1], b0[2], b0[3], b1[0], b1[1], b1[2], b1[3] };
                oacc[hb] = mfma_bf16(vf0, pa0, oacc[hb]);
                oacc[hb] = mfma_bf16(vf1, pa1, oacc[hb]);
            }
        }
    }

    // cross-wave (kh pair) merge
    mred[wv][l] = mrun;
    lred[wv][l] = lrun;
    __syncthreads();
    const float m0v = mred[qg * 2][l],     l0v = lred[qg * 2][l];
    const float m1v = mred[qg * 2 + 1][l], l1v = lred[qg * 2 + 1][l];
    const float M = fmaxf(m0v, m1v);
    const float alpha = __expf(mrun - M);
    const float Lsum = l0v * __expf(m0v - M) + l1v * __expf(m1v - M);
    #pragma unroll
    for (int hb = 0; hb < 4; ++hb) oacc[hb] *= alpha;

    if (kh == 1) {
        #pragma unroll
        for (int hb = 0; hb < 4; ++hb)
            *reinterpret_cast<f32x4*>(&Om[qg][l][hb * 4]) = oacc[hb];
    }
    __syncthreads();
    if (kh == 0) {
        const float inv = 1.0f / Lsum;
        #pragma unroll
        for (int hb = 0; hb < 4; ++hb) {
            const f32x4 o2 = *reinterpret_cast<const f32x4*>(&Om[qg][l][hb * 4]);
            float4 o;
            o.x = (oacc[hb][0] + o2[0]) * inv;
            o.y = (oacc[hb][1] + o2[1]) * inv;
            o.z = (oacc[hb][2] + o2[2]) * inv;
            o.w = (oacc[hb][3] + o2[3]) * inv;
            *reinterpret_cast<float4*>(
                &out[((size_t)b * T_SEQ + qrow) * H_DIM + hb * 16 + 4 * g]) = o;
        }
    }
}

// ---------------------------------------------------------------------------
extern "C" void kernel_launch(void* const* d_in, const int* in_sizes, int n_in,
                              void* d_out, int out_size, void* d_ws, size_t ws_size,
                              hipStream_t stream) {
    const float* x  = (const float*)d_in[0];
    const float* Wq = (const float*)d_in[1];
    const float* Wk = (const float*)d_in[2];
    const float* Wv = (const float*)d_in[3];

    unsigned short* Qg  = (unsigned short*)d_ws;
    unsigned short* Kg  = Qg + (size_t)M_TOT * H_DIM;
    unsigned short* Vtg = Kg + (size_t)M_TOT * H_DIM;
    unsigned short* WF  = Vtg + (size_t)M_TOT * H_DIM;   // 384 KB
    float* o = (float*)d_out;

    wtrans_kernel<<<48, 256, 0, stream>>>(Wq, Wk, Wv, WF);
    qkv_proj_kernel<<<M_TOT / 16, 256, 0, stream>>>(x, WF, Qg, Kg, Vtg);
    attn_kernel<<<512, 256, 0, stream>>>(Qg, Kg, Vtg, o);
}

// Round 18
// 57.625 us; speedup vs baseline: 1.3493x; 1.2668x over previous
//
#include <hip/hip_runtime.h>

#define D_DIM 1024
#define H_DIM 64
#define T_SEQ 2048
#define B_SZ  8
#define M_TOT (B_SZ * T_SEQ)

typedef __attribute__((ext_vector_type(4))) float f32x4;
typedef __attribute__((ext_vector_type(8))) short s16x8;
typedef __attribute__((ext_vector_type(8))) unsigned short u16x8;
typedef __attribute__((ext_vector_type(4))) unsigned short u16x4;

__device__ __forceinline__ unsigned short f2bf(float x) {
    union { float f; unsigned u; } v; v.f = x;
    unsigned r = (v.u + 0x7FFFu + ((v.u >> 16) & 1u)) >> 16;   // RNE
    return (unsigned short)r;
}
__device__ __forceinline__ float bf2f(unsigned short u) {
    union { unsigned u; float f; } v; v.u = ((unsigned)u) << 16; return v.f;
}
__device__ __forceinline__ f32x4 mfma_bf16(u16x8 a, u16x8 b, f32x4 c) {
    return __builtin_amdgcn_mfma_f32_16x16x32_bf16(
        __builtin_bit_cast(s16x8, a), __builtin_bit_cast(s16x8, b), c, 0, 0, 0);
}

// ---------------------------------------------------------------------------
// Kernel 0: W fp32 [1024][64] (x3) -> WF bf16 in MFMA B-fragment order.
// fid = ks*24 + (mat*4+colTile)*2 + kh ; each fragment = contiguous 1KB.
// ---------------------------------------------------------------------------
__global__ __launch_bounds__(256) void wtrans_kernel(
    const float* __restrict__ Wq, const float* __restrict__ Wk,
    const float* __restrict__ Wv, unsigned short* __restrict__ WF)
{
    __shared__ unsigned short tw[64 * 72];
    const int mat = blockIdx.x / 16;
    const int k0  = (blockIdx.x % 16) * 64;
    const int ks  = k0 >> 6;
    const float* W = (mat == 0) ? Wq : (mat == 1) ? Wk : Wv;
    const int tid = threadIdx.x;

    {
        const int r = tid >> 2, c0 = (tid & 3) * 16;
        #pragma unroll
        for (int jj = 0; jj < 4; ++jj) {
            float4 v = *reinterpret_cast<const float4*>(&W[(size_t)(k0 + r) * H_DIM + c0 + jj * 4]);
            u16x4 u = { f2bf(v.x), f2bf(v.y), f2bf(v.z), f2bf(v.w) };
            *reinterpret_cast<u16x4*>(&tw[r * 72 + c0 + jj * 4]) = u;
        }
    }
    __syncthreads();
    #pragma unroll
    for (int sb = 0; sb < 2; ++sb) {
        const int s    = sb * 256 + tid;
        const int ct_l = s >> 7;
        const int kh   = (s >> 6) & 1;
        const int lane = s & 63;
        const int gg = lane >> 4, nn = lane & 15;
        const int cl = ct_l * 16 + nn;
        const int kl = kh * 32 + gg * 8;
        unsigned short tmp[8];
        #pragma unroll
        for (int t = 0; t < 8; ++t) tmp[t] = tw[(kl + t) * 72 + cl];
        const int fid = ks * 24 + (mat * 4 + ct_l) * 2 + kh;
        *reinterpret_cast<u16x8*>(&WF[((size_t)fid * 64 + lane) * 8]) =
            *reinterpret_cast<const u16x8*>(tmp);
    }
}

// ---------------------------------------------------------------------------
// Kernel 1: QKV projection v13.  M=16/block, grid 1024, 512 THREADS = 8 waves:
// wave = (wc = col group 0..3, kp = K-half 0..1). 2x the waves/CU of v9
// (32 waves/CU), half the burst loads and half the K-chain per wave.
// Partial accs merged through LDS (aliased over xs after a barrier).
// ---------------------------------------------------------------------------
__global__ __launch_bounds__(512) void qkv_proj_kernel(
    const float* __restrict__ x, const unsigned short* __restrict__ WF,
    unsigned short* __restrict__ Qg, unsigned short* __restrict__ Kg,
    unsigned short* __restrict__ Vtg)
{
    __shared__ unsigned short xs[16 * 1040];   // 33,280 B; later aliased:
                                               //   accbuf = float[4][64][12] (12,288 B)
                                               //   vt     = u16[64*24] at xs+6144... placed after accbuf
    const int tid = threadIdx.x;
    const int w = tid >> 6, l = tid & 63, g = l >> 4, n = l & 15;
    const int wc = w & 3;          // column group: cols wc*48 .. wc*48+47
    const int kp = w >> 2;         // K half: ks in [kp*8, kp*8+8)
    const int m0 = blockIdx.x * 16;

    // ---- stage whole 16x1024 x panel: 8 float4/thread (512 thr), burst ----
    {
        const f32x4* x4 = reinterpret_cast<const f32x4*>(x + (size_t)m0 * D_DIM);
        f32x4 st[8];
        #pragma unroll
        for (int j = 0; j < 8; ++j) st[j] = x4[j * 512 + tid];
        #pragma unroll
        for (int j = 0; j < 8; ++j) {
            const int u = j * 512 + tid;            // f32x4 unit 0..4095
            const int row = u >> 8, col = (u & 255) * 4;
            u16x4 v = { f2bf(st[j][0]), f2bf(st[j][1]), f2bf(st[j][2]), f2bf(st[j][3]) };
            *reinterpret_cast<u16x4*>(&xs[row * 1040 + col]) = v;
        }
    }
    __syncthreads();

    // ---- barrier-free 8-step K-loop (this wave's K half) ----
    const unsigned short* wfb = WF + ((size_t)(wc * 3) * 2 * 64 + l) * 8;
#define WFRAG(ks, ct, kh) \
    (*reinterpret_cast<const u16x8*>(wfb + (((ks) * 24 + (ct) * 2 + (kh)) * 64) * 8))

    const int ksbase = kp * 8;
    u16x8 cw00 = WFRAG(ksbase, 0, 0), cw10 = WFRAG(ksbase, 1, 0), cw20 = WFRAG(ksbase, 2, 0);
    u16x8 cw01 = WFRAG(ksbase, 0, 1), cw11 = WFRAG(ksbase, 1, 1), cw21 = WFRAG(ksbase, 2, 1);

    f32x4 acc0 = {0.f,0.f,0.f,0.f}, acc1 = {0.f,0.f,0.f,0.f}, acc2 = {0.f,0.f,0.f,0.f};

    #pragma unroll
    for (int i = 0; i < 8; ++i) {
        const int ks = ksbase + i;
        const u16x8 u00 = cw00, u10 = cw10, u20 = cw20;
        const u16x8 u01 = cw01, u11 = cw11, u21 = cw21;
        if (i < 7) {
            cw00 = WFRAG(ks + 1, 0, 0); cw10 = WFRAG(ks + 1, 1, 0);
            cw20 = WFRAG(ks + 1, 2, 0); cw01 = WFRAG(ks + 1, 0, 1);
            cw11 = WFRAG(ks + 1, 1, 1); cw21 = WFRAG(ks + 1, 2, 1);
        }
        const u16x8 af0 = *reinterpret_cast<const u16x8*>(&xs[n * 1040 + ks * 64 + g * 8]);
        const u16x8 af1 = *reinterpret_cast<const u16x8*>(&xs[n * 1040 + ks * 64 + 32 + g * 8]);
        acc0 = mfma_bf16(af0, u00, acc0);
        acc1 = mfma_bf16(af0, u10, acc1);
        acc2 = mfma_bf16(af0, u20, acc2);
        acc0 = mfma_bf16(af1, u01, acc0);
        acc1 = mfma_bf16(af1, u11, acc1);
        acc2 = mfma_bf16(af1, u21, acc2);
    }
#undef WFRAG

    // ---- merge K-halves via LDS (aliased over xs after barrier) ----
    __syncthreads();                                   // all xs reads done
    float* accbuf = reinterpret_cast<float*>(xs);      // [4][64][12] = 12,288 B
    unsigned short* vt = xs + 6144;                    // u16[64*24] = 3 KB, after accbuf

    if (kp == 1) {
        float* dst = &accbuf[(wc * 64 + l) * 12];
        #pragma unroll
        for (int r = 0; r < 4; ++r) { dst[r] = acc0[r]; dst[4 + r] = acc1[r]; dst[8 + r] = acc2[r]; }
    }
    __syncthreads();

    const int b = m0 >> 11, t0 = m0 & (T_SEQ - 1);
    if (kp == 0) {
        const float* src = &accbuf[(wc * 64 + l) * 12];
        #pragma unroll
        for (int r = 0; r < 4; ++r) { acc0[r] += src[r]; acc1[r] += src[4 + r]; acc2[r] += src[8 + r]; }

        // epilogue: D layout col = lane&15, row = (lane>>4)*4 + reg
        const f32x4 accs[3] = { acc0, acc1, acc2 };
        #pragma unroll
        for (int ct = 0; ct < 3; ++ct) {
            const int c = wc * 48 + ct * 16 + n;
            #pragma unroll
            for (int r = 0; r < 4; ++r) {
                const int rin = g * 4 + r;
                const float val = accs[ct][r];
                if (c < 64)
                    Qg[(size_t)(m0 + rin) * H_DIM + c] = f2bf(val * 0.125f);
                else if (c < 128)
                    Kg[(size_t)(m0 + rin) * H_DIM + (c - 64)] = f2bf(val);
                else
                    vt[(c - 128) * 24 + rin] = f2bf(val);
            }
        }
    }
    __syncthreads();
    if (tid < 256) {   // Vt[b][h][t]: 64h x 16t, one u16x4 per thread
        const int h = tid >> 2, c4 = (tid & 3) * 4;
        *reinterpret_cast<u16x4*>(&Vtg[((size_t)(b * 64 + h)) * T_SEQ + t0 + c4]) =
            *reinterpret_cast<const u16x4*>(&vt[h * 24 + c4]);
    }
}

// ---------------------------------------------------------------------------
// Kernel 2: causal flash attention (unchanged PASS since round 5).
// ---------------------------------------------------------------------------
__global__ __launch_bounds__(256) void attn_kernel(
    const unsigned short* __restrict__ Qg, const unsigned short* __restrict__ Kg,
    const unsigned short* __restrict__ Vtg, float* __restrict__ out)
{
    __shared__ unsigned short Kl[128 * 72];   // [key][h]
    __shared__ unsigned short Vl[64 * 136];   // [h][key]
    __shared__ float Om[2][64][20];           // merge buffer
    __shared__ float mred[4][64], lred[4][64];

    const int tid = threadIdx.x;
    const int wv = tid >> 6, qg = wv >> 1, kh = wv & 1;
    const int l = tid & 63, g = l >> 4, n = l & 15;

    const int i = blockIdx.x, hi = i >> 8, rest = i & 255;
    const int b = hi * 4 + (rest >> 6), j = rest & 63;
    const int qt = hi ? (63 - j) : j;
    const int q0 = qt * 32;
    const int qrow = q0 + qg * 16 + n;
    const int qmax = q0 + qg * 16 + 15;
    const int nk = (qt >> 2) + 1;

    const unsigned short* Qb = Qg + (size_t)b * T_SEQ * H_DIM;
    const unsigned short* Kb = Kg + (size_t)b * T_SEQ * H_DIM;
    const unsigned short* Vb = Vtg + (size_t)b * H_DIM * T_SEQ;

    const u16x8 qf0 = *reinterpret_cast<const u16x8*>(&Qb[(size_t)qrow * H_DIM + g * 8]);
    const u16x8 qf1 = *reinterpret_cast<const u16x8*>(&Qb[(size_t)qrow * H_DIM + 32 + g * 8]);

    f32x4 oacc[4];
    #pragma unroll
    for (int hb = 0; hb < 4; ++hb) oacc[hb] = f32x4{0.f, 0.f, 0.f, 0.f};
    float mrun = -1e30f, lrun = 0.f;

    u16x8 kst[4], vst[4];
    #pragma unroll
    for (int ii = 0; ii < 4; ++ii) {
        const int u = tid + ii * 256;
        const int kr = u >> 3, kc = (u & 7) * 8;
        const int vh = u >> 4, vc = (u & 15) * 8;
        kst[ii] = *reinterpret_cast<const u16x8*>(&Kb[(size_t)kr * H_DIM + kc]);
        vst[ii] = *reinterpret_cast<const u16x8*>(&Vb[(size_t)vh * T_SEQ + vc]);
    }

    for (int t = 0; t < nk; ++t) {
        __syncthreads();
        #pragma unroll
        for (int ii = 0; ii < 4; ++ii) {
            const int u = tid + ii * 256;
            const int kr = u >> 3, kc = (u & 7) * 8;
            const int vh = u >> 4, vc = (u & 15) * 8;
            *reinterpret_cast<u16x8*>(&Kl[kr * 72 + kc]) = kst[ii];
            *reinterpret_cast<u16x8*>(&Vl[vh * 136 + vc]) = vst[ii];
        }
        __syncthreads();
        if (t + 1 < nk) {
            const int k0n = (t + 1) * 128;
            #pragma unroll
            for (int ii = 0; ii < 4; ++ii) {
                const int u = tid + ii * 256;
                const int kr = u >> 3, kc = (u & 7) * 8;
                const int vh = u >> 4, vc = (u & 15) * 8;
                kst[ii] = *reinterpret_cast<const u16x8*>(&Kb[(size_t)(k0n + kr) * H_DIM + kc]);
                vst[ii] = *reinterpret_cast<const u16x8*>(&Vb[(size_t)vh * T_SEQ + k0n + vc]);
            }
        }

        const int kbase = kh * 64;
        if (t * 128 + kbase <= qmax) {
            f32x4 s[4];
            #pragma unroll
            for (int kb = 0; kb < 4; ++kb) {
                const u16x8 kf0 = *reinterpret_cast<const u16x8*>(&Kl[(kbase + kb * 16 + n) * 72 + g * 8]);
                const u16x8 kf1 = *reinterpret_cast<const u16x8*>(&Kl[(kbase + kb * 16 + n) * 72 + 32 + g * 8]);
                f32x4 z = f32x4{0.f, 0.f, 0.f, 0.f};
                z = mfma_bf16(kf0, qf0, z);
                z = mfma_bf16(kf1, qf1, z);
                s[kb] = z;
            }

            float sv[16];
            float tmax = -1e30f;
            #pragma unroll
            for (int kb = 0; kb < 4; ++kb)
                #pragma unroll
                for (int r = 0; r < 4; ++r) {
                    const int kk = t * 128 + kbase + kb * 16 + g * 4 + r;
                    float v = s[kb][r];
                    v = (kk <= qrow) ? v : -1e30f;
                    sv[kb * 4 + r] = v;
                    tmax = fmaxf(tmax, v);
                }
            tmax = fmaxf(tmax, __shfl_xor(tmax, 16));
            tmax = fmaxf(tmax, __shfl_xor(tmax, 32));
            const float mnew = fmaxf(mrun, tmax);
            const float scale = __expf(mrun - mnew);
            #pragma unroll
            for (int hb = 0; hb < 4; ++hb) oacc[hb] *= scale;
            lrun = lrun * scale;
            mrun = mnew;

            unsigned short pb[16];
            float ps = 0.f;
            #pragma unroll
            for (int q = 0; q < 16; ++q) {
                const float p = (sv[q] > -1e29f) ? __expf(sv[q] - mnew) : 0.f;
                pb[q] = f2bf(p);
                ps += bf2f(pb[q]);
            }
            ps += __shfl_xor(ps, 16);
            ps += __shfl_xor(ps, 32);
            lrun += ps;

            u16x8 pa0, pa1;
            #pragma unroll
            for (int q = 0; q < 8; ++q) { pa0[q] = pb[q]; pa1[q] = pb[8 + q]; }

            #pragma unroll
            for (int hb = 0; hb < 4; ++hb) {
                const unsigned short* vp = &Vl[(hb * 16 + n) * 136 + kbase + 4 * g];
                const u16x4 a0 = *reinterpret_cast<const u16x4*>(vp);
                const u16x4 a1 = *reinterpret_cast<const u16x4*>(vp + 16);
                const u16x4 b0 = *reinterpret_cast<const u16x4*>(vp + 32);
                const u16x4 b1 = *reinterpret_cast<const u16x4*>(vp + 48);
                const u16x8 vf0 = { a0[0], a0[1], a0[2], a0[3], a1[0], a1[1], a1[2], a1[3] };
                const u16x8 vf1 = { b0[0], b0[1], b0[2], b0[3], b1[0], b1[1], b1[2], b1[3] };
                oacc[hb] = mfma_bf16(vf0, pa0, oacc[hb]);
                oacc[hb] = mfma_bf16(vf1, pa1, oacc[hb]);
            }
        }
    }

    // cross-wave (kh pair) merge
    mred[wv][l] = mrun;
    lred[wv][l] = lrun;
    __syncthreads();
    const float m0v = mred[qg * 2][l],     l0v = lred[qg * 2][l];
    const float m1v = mred[qg * 2 + 1][l], l1v = lred[qg * 2 + 1][l];
    const float M = fmaxf(m0v, m1v);
    const float alpha = __expf(mrun - M);
    const float Lsum = l0v * __expf(m0v - M) + l1v * __expf(m1v - M);
    #pragma unroll
    for (int hb = 0; hb < 4; ++hb) oacc[hb] *= alpha;

    if (kh == 1) {
        #pragma unroll
        for (int hb = 0; hb < 4; ++hb)
            *reinterpret_cast<f32x4*>(&Om[qg][l][hb * 4]) = oacc[hb];
    }
    __syncthreads();
    if (kh == 0) {
        const float inv = 1.0f / Lsum;
        #pragma unroll
        for (int hb = 0; hb < 4; ++hb) {
            const f32x4 o2 = *reinterpret_cast<const f32x4*>(&Om[qg][l][hb * 4]);
            float4 o;
            o.x = (oacc[hb][0] + o2[0]) * inv;
            o.y = (oacc[hb][1] + o2[1]) * inv;
            o.z = (oacc[hb][2] + o2[2]) * inv;
            o.w = (oacc[hb][3] + o2[3]) * inv;
            *reinterpret_cast<float4*>(
                &out[((size_t)b * T_SEQ + qrow) * H_DIM + hb * 16 + 4 * g]) = o;
        }
    }
}

// ---------------------------------------------------------------------------
extern "C" void kernel_launch(void* const* d_in, const int* in_sizes, int n_in,
                              void* d_out, int out_size, void* d_ws, size_t ws_size,
                              hipStream_t stream) {
    const float* x  = (const float*)d_in[0];
    const float* Wq = (const float*)d_in[1];
    const float* Wk = (const float*)d_in[2];
    const float* Wv = (const float*)d_in[3];

    unsigned short* Qg  = (unsigned short*)d_ws;
    unsigned short* Kg  = Qg + (size_t)M_TOT * H_DIM;
    unsigned short* Vtg = Kg + (size_t)M_TOT * H_DIM;
    unsigned short* WF  = Vtg + (size_t)M_TOT * H_DIM;   // 384 KB
    float* o = (float*)d_out;

    wtrans_kernel<<<48, 256, 0, stream>>>(Wq, Wk, Wv, WF);
    qkv_proj_kernel<<<M_TOT / 16, 512, 0, stream>>>(x, WF, Qg, Kg, Vtg);
    attn_kernel<<<512, 256, 0, stream>>>(Qg, Kg, Vtg, o);
}